// Round 5
// baseline (284.999 us; speedup 1.0000x reference)
//
#include <hip/hip_runtime.h>
#include <hip/hip_bf16.h>

// GraphSAGE 2-layer, producer-consumer fused:
//   waves 0-3: gather+mean tile t+1 -> LDS buf^1   (latency hidden under GEMM)
//   waves 4-7: MFMA GEMM tile t from LDS buf + global W, relu, store
// N_RAW=200000, N1=100000 (3125 tiles of 32), N2=20000 (625 tiles), D=256, OUT=256.

typedef __attribute__((ext_vector_type(8))) short bf16x8;
typedef __attribute__((ext_vector_type(4))) float f32x4;

static __device__ __forceinline__ short f2bf(float f) {
  __hip_bfloat16 h = __float2bfloat16(f);
  return *reinterpret_cast<short*>(&h);
}
static __device__ __forceinline__ float bf2f(short s) {
  union { unsigned u; float f; } x;
  x.u = ((unsigned)(unsigned short)s) << 16;
  return x.f;
}

// ---------------- one-shot f32 -> bf16: raw (25000 blocks) + W1 (64) + W2 (64) ----------------
// Non-temporal f32 reads: do NOT cache the 205 MB source stream, so the bf16
// destination (rawb, 102 MB) stays LLC-resident for the gather that follows.
__global__ __launch_bounds__(256) void convert_all(
    const float* __restrict__ raw, const float* __restrict__ W1,
    const float* __restrict__ W2, short* __restrict__ rawb,
    short* __restrict__ W1b, short* __restrict__ W2b) {
  const int b = blockIdx.x;
  const float* src;
  short* dst;
  size_t base;
  if (b < 25000) { src = raw; dst = rawb; base = (size_t)b * 2048; }
  else if (b < 25064) { src = W1; dst = W1b; base = (size_t)(b - 25000) * 2048; }
  else { src = W2; dst = W2b; base = (size_t)(b - 25064) * 2048; }
  const size_t i = base + (size_t)threadIdx.x * 8;
  const f32x4* s4 = reinterpret_cast<const f32x4*>(src + i);
  f32x4 u = __builtin_nontemporal_load(s4);
  f32x4 v = __builtin_nontemporal_load(s4 + 1);
  bf16x8 o;
  o[0] = f2bf(u.x); o[1] = f2bf(u.y); o[2] = f2bf(u.z); o[3] = f2bf(u.w);
  o[4] = f2bf(v.x); o[5] = f2bf(v.y); o[6] = f2bf(v.z); o[7] = f2bf(v.w);
  *reinterpret_cast<bf16x8*>(dst + i) = o;
}

// ---------------- fused producer/consumer layer kernel ----------------
// 512 threads: tid<256 producers (gather+mean -> LDS), tid>=256 consumers (GEMM).
// Persistent: block handles tiles t0, t0+grid, ... Double-buffered LDS.
template <bool OUT_BF16>
__global__ __launch_bounds__(512, 4) void sage_pc(
    const short* __restrict__ E,        // [Ne][256] bf16 embeddings
    const int* __restrict__ self_idx,   // [Nv]
    const int* __restrict__ neigh,      // [Nv][10]
    const short* __restrict__ Wb,       // [256][512] bf16 (W row-major)
    void* __restrict__ out,             // [Nv][256] (bf16 or f32)
    int ntiles) {
  __shared__ short As[2][32][520];  // row stride 1040 B -> only free 2-way conflicts

  const int tid = threadIdx.x;
  const int nblk = gridDim.x;
  const int t0 = blockIdx.x;

  // ---------------- producer: gather+mean tile t into As[buf] ----------------
  auto gather = [&](int t, int buf) __attribute__((always_inline)) {
    const int c = tid & 31;    // 16-B chunk (8 bf16) within 256-col row
    const int rs = tid >> 5;   // row slot 0..7 -> rows rs*4 .. rs*4+3
#pragma unroll
    for (int rr = 0; rr < 4; ++rr) {
      const int r = rs * 4 + rr;
      const int gr = t * 32 + r;
      const int si = self_idx[gr];
      int nbx[10];
#pragma unroll
      for (int k = 0; k < 10; ++k) nbx[k] = neigh[gr * 10 + k];
      bf16x8 sv = *reinterpret_cast<const bf16x8*>(E + (size_t)si * 256 + c * 8);
      bf16x8 v[10];
#pragma unroll
      for (int k = 0; k < 10; ++k)
        v[k] = *reinterpret_cast<const bf16x8*>(E + (size_t)nbx[k] * 256 + c * 8);
      bf16x8 mv;
#pragma unroll
      for (int j = 0; j < 8; ++j) {
        float sA = bf2f(v[0][j]) + bf2f(v[2][j]) + bf2f(v[4][j]) + bf2f(v[6][j]) + bf2f(v[8][j]);
        float sB = bf2f(v[1][j]) + bf2f(v[3][j]) + bf2f(v[5][j]) + bf2f(v[7][j]) + bf2f(v[9][j]);
        mv[j] = f2bf((sA + sB) * 0.1f);
      }
      *reinterpret_cast<bf16x8*>(&As[buf][r][c * 8]) = sv;
      *reinterpret_cast<bf16x8*>(&As[buf][r][256 + c * 8]) = mv;
    }
  };

  // prologue: fill As[0] with tile t0
  if (tid < 256) gather(t0, 0);
  __syncthreads();

  int buf = 0;
  for (int t = t0; t < ntiles; t += nblk, buf ^= 1) {
    if (tid < 256) {
      // ---------------- producer: gather next tile ----------------
      const int tn = t + nblk;
      if (tn < ntiles) gather(tn, buf ^ 1);
    } else {
      // ---------------- consumer: GEMM 32x256, K=512, 1-step pipelined ----------------
      const int wave = (tid >> 6) - 4;
      const int lane = tid & 63;
      const int wn = wave * 64;
      const int lr = lane & 15;           // m (A) / n (B) within 16x16 frag
      const int lkb = (lane >> 4) * 8;    // k base within 32
      const short* Bp = Wb + (size_t)(wn + lr) * 512 + lkb;  // + ni*8192 + k0

      f32x4 acc[2][4] = {};

      bf16x8 a0 = *reinterpret_cast<const bf16x8*>(&As[buf][lr][lkb]);
      bf16x8 a1 = *reinterpret_cast<const bf16x8*>(&As[buf][16 + lr][lkb]);
      bf16x8 b0 = *reinterpret_cast<const bf16x8*>(Bp + 0 * 8192);
      bf16x8 b1 = *reinterpret_cast<const bf16x8*>(Bp + 1 * 8192);
      bf16x8 b2 = *reinterpret_cast<const bf16x8*>(Bp + 2 * 8192);
      bf16x8 b3 = *reinterpret_cast<const bf16x8*>(Bp + 3 * 8192);

#pragma unroll
      for (int ks = 0; ks < 16; ++ks) {
        bf16x8 na0, na1, nb0, nb1, nb2, nb3;
        if (ks < 15) {
          const int k0 = (ks + 1) * 32;
          na0 = *reinterpret_cast<const bf16x8*>(&As[buf][lr][k0 + lkb]);
          na1 = *reinterpret_cast<const bf16x8*>(&As[buf][16 + lr][k0 + lkb]);
          nb0 = *reinterpret_cast<const bf16x8*>(Bp + k0 + 0 * 8192);
          nb1 = *reinterpret_cast<const bf16x8*>(Bp + k0 + 1 * 8192);
          nb2 = *reinterpret_cast<const bf16x8*>(Bp + k0 + 2 * 8192);
          nb3 = *reinterpret_cast<const bf16x8*>(Bp + k0 + 3 * 8192);
        }
        __builtin_amdgcn_s_setprio(1);
        acc[0][0] = __builtin_amdgcn_mfma_f32_16x16x32_bf16(a0, b0, acc[0][0], 0, 0, 0);
        acc[1][0] = __builtin_amdgcn_mfma_f32_16x16x32_bf16(a1, b0, acc[1][0], 0, 0, 0);
        acc[0][1] = __builtin_amdgcn_mfma_f32_16x16x32_bf16(a0, b1, acc[0][1], 0, 0, 0);
        acc[1][1] = __builtin_amdgcn_mfma_f32_16x16x32_bf16(a1, b1, acc[1][1], 0, 0, 0);
        acc[0][2] = __builtin_amdgcn_mfma_f32_16x16x32_bf16(a0, b2, acc[0][2], 0, 0, 0);
        acc[1][2] = __builtin_amdgcn_mfma_f32_16x16x32_bf16(a1, b2, acc[1][2], 0, 0, 0);
        acc[0][3] = __builtin_amdgcn_mfma_f32_16x16x32_bf16(a0, b3, acc[0][3], 0, 0, 0);
        acc[1][3] = __builtin_amdgcn_mfma_f32_16x16x32_bf16(a1, b3, acc[1][3], 0, 0, 0);
        __builtin_amdgcn_s_setprio(0);
        a0 = na0; a1 = na1; b0 = nb0; b1 = nb1; b2 = nb2; b3 = nb3;
      }

      // epilogue: relu + store
#pragma unroll
      for (int mi = 0; mi < 2; ++mi)
#pragma unroll
        for (int ni = 0; ni < 4; ++ni)
#pragma unroll
          for (int r = 0; r < 4; ++r) {
            const int gm = t * 32 + mi * 16 + (lane >> 4) * 4 + r;
            const int gn = wn + ni * 16 + lr;
            float v = acc[mi][ni][r];
            v = v > 0.f ? v : 0.f;
            if (OUT_BF16)
              reinterpret_cast<short*>(out)[(size_t)gm * 256 + gn] = f2bf(v);
            else
              reinterpret_cast<float*>(out)[(size_t)gm * 256 + gn] = v;
          }
    }
    __syncthreads();
  }
}

extern "C" void kernel_launch(void* const* d_in, const int* in_sizes, int n_in,
                              void* d_out, int out_size, void* d_ws, size_t ws_size,
                              hipStream_t stream) {
  const float* raw = (const float*)d_in[0];
  const float* W1 = (const float*)d_in[1];
  const float* W2 = (const float*)d_in[2];
  const int* nodes1 = (const int*)d_in[3];
  const int* neigh1 = (const int*)d_in[4];
  const int* self2 = (const int*)d_in[5];
  const int* neigh2 = (const int*)d_in[6];
  float* out = (float*)d_out;

  const int N_RAW = 200000, N1 = 100000;

  short* rawb = (short*)d_ws;                         // 200000*256 bf16 = 102.4 MB
  short* h1 = rawb + (size_t)N_RAW * 256;             // 100000*256 bf16 = 51.2 MB
  short* W1b = h1 + (size_t)N1 * 256;                 // 131072 bf16
  short* W2b = W1b + 131072;                          // 131072 bf16

  convert_all<<<25128, 256, 0, stream>>>(raw, W1, W2, rawb, W1b, W2b);
  sage_pc<true><<<512, 512, 0, stream>>>(rawb, nodes1, neigh1, W1b, h1, 3125);
  sage_pc<false><<<512, 512, 0, stream>>>(h1, self2, neigh2, W2b, out, 625);
}